// Round 1
// baseline (1585.745 us; speedup 1.0000x reference)
//
#include <hip/hip_runtime.h>

// BandSplit: x(8,2000,481,2) f32 -> out(8,128,2000,34) f32
// out[b,c,t,j] = rinv[b,j] * dot(x[b,t,seg_j], CW_j[c,:]) + beta[b,j,c]
//   CW = nw*fw,  beta = fb + S1 - mu*rinv*S2,  S1=dot(nb,fw), S2=dot(nw,fw)

#define T_DIM 2000
#define C_DIM 128
#define K_DIM 962
#define NCOLS 34
#define EPSV 1e-5f

#define WS_STATS 0          // 272 float2 = 544 floats
#define WS_CW    1024       // 962*128 floats
#define WS_BETA  (1024 + 962*128)   // 8*34*128 floats
// total ws need = 158,976 floats = 635,904 bytes

__constant__ int COL_K0[NCOLS] = {
  0,
  10,18,26,34,42,50,58,66,74,82,90,98,106,114,122,130,138,146,154,
  162,182,202,222,242,262,
  282,362,442,522,602,682,762,
  842};
__constant__ int COL_W[NCOLS] = {
  10,
  8,8,8,8,8,8,8,8,8,8,8,8,8,8,8,8,8,8,8,
  20,20,20,20,20,20,
  80,80,80,80,80,80,80,
  120};
__constant__ int COL_G[NCOLS] = {
  0,
  1,1,1,1,1,1,1,1,1,1,1,1,1,1,1,1,1,1,1,
  2,2,2,2,2,2,
  3,3,3,3,3,3,3,
  4};
__constant__ int COL_NI[NCOLS] = {
  0,
  0,1,2,3,4,5,6,7,8,9,10,11,12,13,14,15,16,17,18,
  0,1,2,3,4,5,
  0,1,2,3,4,5,6,
  0};

// ---------------- stats: mu, rinv per (b, col) ----------------
__global__ __launch_bounds__(512) void stats_k(const float* __restrict__ x,
                                               float* __restrict__ ws) {
  const int j = blockIdx.x, b = blockIdx.y;
  const int w = COL_W[j], k0 = COL_K0[j];
  const float* xb = x + (size_t)b * T_DIM * K_DIM + k0;
  float s = 0.f, s2 = 0.f;
  for (int t = threadIdx.x; t < T_DIM; t += 512) {
    const float* row = xb + (size_t)t * K_DIM;
    for (int i = 0; i < w; i += 2) {
      float2 v = *(const float2*)(row + i);
      s  += v.x + v.y;
      s2 += v.x * v.x + v.y * v.y;
    }
  }
  __shared__ float rs[512];
  __shared__ float rq[512];
  rs[threadIdx.x] = s; rq[threadIdx.x] = s2;
  __syncthreads();
  for (int off = 256; off > 0; off >>= 1) {
    if (threadIdx.x < off) {
      rs[threadIdx.x] += rs[threadIdx.x + off];
      rq[threadIdx.x] += rq[threadIdx.x + off];
    }
    __syncthreads();
  }
  if (threadIdx.x == 0) {
    float n = (float)(T_DIM * w);
    float mu = rs[0] / n;
    float var = rq[0] / n - mu * mu;
    float rinv = rsqrtf(var + EPSV);
    ws[WS_STATS + 2 * (b * NCOLS + j)]     = mu;
    ws[WS_STATS + 2 * (b * NCOLS + j) + 1] = rinv;
  }
}

// ---------------- prep: CW[k][c] = nw*fw (k-major), beta[b][j][c] ----------------
__global__ __launch_bounds__(128) void prep_k(
    const float* __restrict__ nw0, const float* __restrict__ nb0,
    const float* __restrict__ fw0, const float* __restrict__ fb0,
    const float* __restrict__ nw1, const float* __restrict__ nb1,
    const float* __restrict__ fw1, const float* __restrict__ fb1,
    const float* __restrict__ nw2, const float* __restrict__ nb2,
    const float* __restrict__ fw2, const float* __restrict__ fb2,
    const float* __restrict__ nw3, const float* __restrict__ nb3,
    const float* __restrict__ fw3, const float* __restrict__ fb3,
    const float* __restrict__ nw4, const float* __restrict__ nb4,
    const float* __restrict__ fw4, const float* __restrict__ fb4,
    float* __restrict__ ws) {
  const int j = blockIdx.x, c = threadIdx.x;
  const int g = COL_G[j], ni = COL_NI[j], w = COL_W[j], k0 = COL_K0[j];
  const float *nw, *nb, *fw, *fb;
  switch (g) {
    case 0: nw = nw0; nb = nb0; fw = fw0; fb = fb0; break;
    case 1: nw = nw1; nb = nb1; fw = fw1; fb = fb1; break;
    case 2: nw = nw2; nb = nb2; fw = fw2; fb = fb2; break;
    case 3: nw = nw3; nb = nb3; fw = fw3; fb = fb3; break;
    default: nw = nw4; nb = nb4; fw = fw4; fb = fb4; break;
  }
  const float* fwr = fw + ((size_t)ni * C_DIM + c) * w;
  const float* nwr = nw + (size_t)ni * w;
  const float* nbr = nb + (size_t)ni * w;
  float s1 = 0.f, s2 = 0.f;
  float* cw = ws + WS_CW;
  for (int i = 0; i < w; ++i) {
    float f = fwr[i];
    float cwv = nwr[i] * f;
    s1 += nbr[i] * f;
    s2 += cwv;
    cw[(size_t)(k0 + i) * C_DIM + c] = cwv;
  }
  float fbv = fb[(size_t)ni * C_DIM + c];
  for (int b = 0; b < 8; ++b) {
    float mu   = ws[WS_STATS + 2 * (b * NCOLS + j)];
    float rinv = ws[WS_STATS + 2 * (b * NCOLS + j) + 1];
    ws[WS_BETA + (size_t)(b * NCOLS + j) * C_DIM + c] = fbv + s1 - mu * rinv * s2;
  }
}

// ---------------- main: per block (b, t0:64, c0:64), loop 34 cols ----------------
#define TT 64
#define CC 64
#define XPAD 124   // 64*124*4 = 31744 B

__global__ __launch_bounds__(256) void main_k(const float* __restrict__ x,
                                              const float* __restrict__ ws,
                                              float* __restrict__ out) {
  __shared__ float lx[TT * XPAD];   // 31744 B
  __shared__ float lw[120 * CC];    // 30720 B
  const int tid = threadIdx.x;
  const int t0 = blockIdx.x * TT;
  const int c0 = blockIdx.y * CC;
  const int b  = blockIdx.z;
  const float* xb   = x + (size_t)b * T_DIM * K_DIM;
  const float* cw   = ws + WS_CW;
  const float* beta = ws + WS_BETA;

  const int tt  = (tid >> 4) << 2;  // thread tile t offset 0..60
  const int cc4 = (tid & 15) << 2;  // thread tile c offset 0..60
  const int sr   = tid >> 2;        // x staging row 0..63
  const int ssub = tid & 3;
  const int wr = tid >> 4;          // W staging k row 0..15
  const int wq = (tid & 15) << 2;   // W staging c quad

  for (int j = 0; j < NCOLS; ++j) {
    const int w = COL_W[j], k0 = COL_K0[j];
    // stage X tile: rows t0..t0+63, w floats each
    {
      const int hw = w >> 1;
      const int trow = t0 + sr;
      float* dst = lx + sr * XPAD;
      if (trow < T_DIM) {
        const float* src = xb + (size_t)trow * K_DIM + k0;
        for (int ii = ssub; ii < hw; ii += 4) {
          *(float2*)(dst + 2 * ii) = *(const float2*)(src + 2 * ii);
        }
      } else {
        for (int ii = ssub; ii < hw; ii += 4) {
          *(float2*)(dst + 2 * ii) = make_float2(0.f, 0.f);
        }
      }
    }
    // stage W chunk: w rows x 64 c (from k-major CW -> coalesced)
    for (int i = wr; i < w; i += 16) {
      *(float4*)(lw + i * CC + wq) =
          *(const float4*)(cw + (size_t)(k0 + i) * C_DIM + c0 + wq);
    }
    __syncthreads();

    // compute 4t x 4c register tile
    float acc[4][4] = {};
    int kk = 0;
    for (; kk + 4 <= w; kk += 4) {
      float4 xa[4];
      #pragma unroll
      for (int i = 0; i < 4; ++i)
        xa[i] = *(const float4*)(lx + (tt + i) * XPAD + kk);
      #pragma unroll
      for (int u = 0; u < 4; ++u) {
        float4 wv = *(const float4*)(lw + (kk + u) * CC + cc4);
        #pragma unroll
        for (int i = 0; i < 4; ++i) {
          float xv = (&xa[i].x)[u];
          acc[i][0] += xv * wv.x;
          acc[i][1] += xv * wv.y;
          acc[i][2] += xv * wv.z;
          acc[i][3] += xv * wv.w;
        }
      }
    }
    for (; kk < w; ++kk) {  // remainder (w=10 only)
      float4 wv = *(const float4*)(lw + kk * CC + cc4);
      #pragma unroll
      for (int i = 0; i < 4; ++i) {
        float xv = lx[(tt + i) * XPAD + kk];
        acc[i][0] += xv * wv.x;
        acc[i][1] += xv * wv.y;
        acc[i][2] += xv * wv.z;
        acc[i][3] += xv * wv.w;
      }
    }

    // epilogue: scale + bias + strided store
    const float rinv = ws[WS_STATS + 2 * (b * NCOLS + j) + 1];
    const float* bet = beta + (size_t)(b * NCOLS + j) * C_DIM + c0 + cc4;
    const float b0 = bet[0], b1 = bet[1], b2 = bet[2], b3 = bet[3];
    #pragma unroll
    for (int i = 0; i < 4; ++i) {
      const int t = t0 + tt + i;
      if (t < T_DIM) {
        size_t base = ((size_t)(b * C_DIM + c0 + cc4) * T_DIM + t) * NCOLS + j;
        const size_t cs = (size_t)T_DIM * NCOLS;
        out[base]          = rinv * acc[i][0] + b0;
        out[base + cs]     = rinv * acc[i][1] + b1;
        out[base + 2 * cs] = rinv * acc[i][2] + b2;
        out[base + 3 * cs] = rinv * acc[i][3] + b3;
      }
    }
    __syncthreads();  // protect LDS before next col's staging
  }
}

extern "C" void kernel_launch(void* const* d_in, const int* in_sizes, int n_in,
                              void* d_out, int out_size, void* d_ws, size_t ws_size,
                              hipStream_t stream) {
  const float* x = (const float*)d_in[0];
  float* ws = (float*)d_ws;
  float* out = (float*)d_out;

  stats_k<<<dim3(NCOLS, 8), 512, 0, stream>>>(x, ws);
  prep_k<<<NCOLS, 128, 0, stream>>>(
      (const float*)d_in[1],  (const float*)d_in[2],  (const float*)d_in[3],  (const float*)d_in[4],
      (const float*)d_in[5],  (const float*)d_in[6],  (const float*)d_in[7],  (const float*)d_in[8],
      (const float*)d_in[9],  (const float*)d_in[10], (const float*)d_in[11], (const float*)d_in[12],
      (const float*)d_in[13], (const float*)d_in[14], (const float*)d_in[15], (const float*)d_in[16],
      (const float*)d_in[17], (const float*)d_in[18], (const float*)d_in[19], (const float*)d_in[20],
      ws);
  main_k<<<dim3((T_DIM + TT - 1) / TT, C_DIM / CC, 8), 256, 0, stream>>>(x, ws, out);
}

// Round 2
// 789.050 us; speedup vs baseline: 2.0097x; 2.0097x over previous
//
#include <hip/hip_runtime.h>

// BandSplit: x(8,2000,481,2) f32 -> out(8,128,2000,34) f32
// out[b,c,t,j] = rinv[b,j] * dot(x[b,t,seg_j], CW_j[c,:]) + beta[b,j,c]
//   CW = nw*fw,  beta = fb + S1 - mu*rinv*S2,  S1=dot(nb,fw), S2=dot(nw,fw)
//
// Pass 1 (main_k): GEMM, stores chunked-transposed tmp layout IN d_out:
//   per (b,c) slab of 68000 floats: 8 chunks, chunk q = [34][Tp] (Tp=256,
//   last 208), j-major -> perfectly coalesced full-line stores.
// Pass 2 (transpose_k): per-chunk in-place [34][Tp] -> [Tp][34] via LDS.

#define T_DIM 2000
#define C_DIM 128
#define K_DIM 962
#define NCOLS 34
#define EPSV 1e-5f
#define SLAB 68000        // 2000*34 floats per (b,c)
#define CHUNK_T 256
#define CHUNK_ELEMS (NCOLS * CHUNK_T)   // 8704
#define LAST_T 208        // 2000 - 7*256

#define WS_STATS 0          // 272 float2 = 544 floats
#define WS_CW    1024       // 962*128 floats
#define WS_BETA  (1024 + 962*128)   // 8*34*128 floats

__constant__ int COL_K0[NCOLS] = {
  0,
  10,18,26,34,42,50,58,66,74,82,90,98,106,114,122,130,138,146,154,
  162,182,202,222,242,262,
  282,362,442,522,602,682,762,
  842};
__constant__ int COL_W[NCOLS] = {
  10,
  8,8,8,8,8,8,8,8,8,8,8,8,8,8,8,8,8,8,8,
  20,20,20,20,20,20,
  80,80,80,80,80,80,80,
  120};
__constant__ int COL_G[NCOLS] = {
  0,
  1,1,1,1,1,1,1,1,1,1,1,1,1,1,1,1,1,1,1,
  2,2,2,2,2,2,
  3,3,3,3,3,3,3,
  4};
__constant__ int COL_NI[NCOLS] = {
  0,
  0,1,2,3,4,5,6,7,8,9,10,11,12,13,14,15,16,17,18,
  0,1,2,3,4,5,
  0,1,2,3,4,5,6,
  0};

// ---------------- stats: mu, rinv per (b, col) ----------------
__global__ __launch_bounds__(512) void stats_k(const float* __restrict__ x,
                                               float* __restrict__ ws) {
  const int j = blockIdx.x, b = blockIdx.y;
  const int w = COL_W[j], k0 = COL_K0[j];
  const float* xb = x + (size_t)b * T_DIM * K_DIM + k0;
  float s = 0.f, s2 = 0.f;
  for (int t = threadIdx.x; t < T_DIM; t += 512) {
    const float* row = xb + (size_t)t * K_DIM;
    for (int i = 0; i < w; i += 2) {
      float2 v = *(const float2*)(row + i);
      s  += v.x + v.y;
      s2 += v.x * v.x + v.y * v.y;
    }
  }
  __shared__ float rs[512];
  __shared__ float rq[512];
  rs[threadIdx.x] = s; rq[threadIdx.x] = s2;
  __syncthreads();
  for (int off = 256; off > 0; off >>= 1) {
    if (threadIdx.x < off) {
      rs[threadIdx.x] += rs[threadIdx.x + off];
      rq[threadIdx.x] += rq[threadIdx.x + off];
    }
    __syncthreads();
  }
  if (threadIdx.x == 0) {
    float n = (float)(T_DIM * w);
    float mu = rs[0] / n;
    float var = rq[0] / n - mu * mu;
    float rinv = rsqrtf(var + EPSV);
    ws[WS_STATS + 2 * (b * NCOLS + j)]     = mu;
    ws[WS_STATS + 2 * (b * NCOLS + j) + 1] = rinv;
  }
}

// ---------------- prep: CW[k][c] = nw*fw (k-major), beta[b][j][c] ----------------
__global__ __launch_bounds__(128) void prep_k(
    const float* __restrict__ nw0, const float* __restrict__ nb0,
    const float* __restrict__ fw0, const float* __restrict__ fb0,
    const float* __restrict__ nw1, const float* __restrict__ nb1,
    const float* __restrict__ fw1, const float* __restrict__ fb1,
    const float* __restrict__ nw2, const float* __restrict__ nb2,
    const float* __restrict__ fw2, const float* __restrict__ fb2,
    const float* __restrict__ nw3, const float* __restrict__ nb3,
    const float* __restrict__ fw3, const float* __restrict__ fb3,
    const float* __restrict__ nw4, const float* __restrict__ nb4,
    const float* __restrict__ fw4, const float* __restrict__ fb4,
    float* __restrict__ ws) {
  const int j = blockIdx.x, c = threadIdx.x;
  const int g = COL_G[j], ni = COL_NI[j], w = COL_W[j], k0 = COL_K0[j];
  const float *nw, *nb, *fw, *fb;
  switch (g) {
    case 0: nw = nw0; nb = nb0; fw = fw0; fb = fb0; break;
    case 1: nw = nw1; nb = nb1; fw = fw1; fb = fb1; break;
    case 2: nw = nw2; nb = nb2; fw = fw2; fb = fb2; break;
    case 3: nw = nw3; nb = nb3; fw = fw3; fb = fb3; break;
    default: nw = nw4; nb = nb4; fw = fw4; fb = fb4; break;
  }
  const float* fwr = fw + ((size_t)ni * C_DIM + c) * w;
  const float* nwr = nw + (size_t)ni * w;
  const float* nbr = nb + (size_t)ni * w;
  float s1 = 0.f, s2 = 0.f;
  float* cw = ws + WS_CW;
  for (int i = 0; i < w; ++i) {
    float f = fwr[i];
    float cwv = nwr[i] * f;
    s1 += nbr[i] * f;
    s2 += cwv;
    cw[(size_t)(k0 + i) * C_DIM + c] = cwv;
  }
  float fbv = fb[(size_t)ni * C_DIM + c];
  for (int b = 0; b < 8; ++b) {
    float mu   = ws[WS_STATS + 2 * (b * NCOLS + j)];
    float rinv = ws[WS_STATS + 2 * (b * NCOLS + j) + 1];
    ws[WS_BETA + (size_t)(b * NCOLS + j) * C_DIM + c] = fbv + s1 - mu * rinv * s2;
  }
}

// ---------------- pass 1: per block (b, t0:64, c0:64), loop 34 cols ----------------
#define TT 64
#define CC 64
#define XPAD 124   // 64*124*4 = 31744 B

__global__ __launch_bounds__(256) void main_k(const float* __restrict__ x,
                                              const float* __restrict__ ws,
                                              float* __restrict__ out) {
  __shared__ float lx[TT * XPAD];   // 31744 B
  __shared__ float lw[120 * CC];    // 30720 B
  const int tid = threadIdx.x;
  const int t0 = blockIdx.x * TT;
  const int c0 = blockIdx.y * CC;
  const int b  = blockIdx.z;
  const float* xb   = x + (size_t)b * T_DIM * K_DIM;
  const float* cw   = ws + WS_CW;
  const float* beta = ws + WS_BETA;

  const int tt  = (tid >> 4) << 2;  // thread tile t offset 0..60
  const int cc4 = (tid & 15) << 2;  // thread tile c offset 0..60
  const int sr   = tid >> 2;        // x staging row 0..63
  const int ssub = tid & 3;
  const int wr = tid >> 4;          // W staging k row 0..15
  const int wq = (tid & 15) << 2;   // W staging c quad

  // chunked-tmp addressing (constant per block: 64-tile never crosses 256-chunk)
  const int q  = t0 >> 8;
  const int Tp = (q < 7) ? CHUNK_T : LAST_T;
  const int tp = (t0 & 255) + tt;

  for (int j = 0; j < NCOLS; ++j) {
    const int w = COL_W[j], k0 = COL_K0[j];
    // stage X tile: rows t0..t0+63, w floats each
    {
      const int hw = w >> 1;
      const int trow = t0 + sr;
      float* dst = lx + sr * XPAD;
      if (trow < T_DIM) {
        const float* src = xb + (size_t)trow * K_DIM + k0;
        for (int ii = ssub; ii < hw; ii += 4) {
          *(float2*)(dst + 2 * ii) = *(const float2*)(src + 2 * ii);
        }
      } else {
        for (int ii = ssub; ii < hw; ii += 4) {
          *(float2*)(dst + 2 * ii) = make_float2(0.f, 0.f);
        }
      }
    }
    // stage W chunk: w rows x 64 c (from k-major CW -> coalesced)
    for (int i = wr; i < w; i += 16) {
      *(float4*)(lw + i * CC + wq) =
          *(const float4*)(cw + (size_t)(k0 + i) * C_DIM + c0 + wq);
    }
    __syncthreads();

    // compute 4t x 4c register tile
    float acc[4][4] = {};
    int kk = 0;
    for (; kk + 4 <= w; kk += 4) {
      float4 xa[4];
      #pragma unroll
      for (int i = 0; i < 4; ++i)
        xa[i] = *(const float4*)(lx + (tt + i) * XPAD + kk);
      #pragma unroll
      for (int u = 0; u < 4; ++u) {
        float4 wv = *(const float4*)(lw + (kk + u) * CC + cc4);
        #pragma unroll
        for (int i = 0; i < 4; ++i) {
          float xv = (&xa[i].x)[u];
          acc[i][0] += xv * wv.x;
          acc[i][1] += xv * wv.y;
          acc[i][2] += xv * wv.z;
          acc[i][3] += xv * wv.w;
        }
      }
    }
    for (; kk < w; ++kk) {  // remainder (w=10 only)
      float4 wv = *(const float4*)(lw + kk * CC + cc4);
      #pragma unroll
      for (int i = 0; i < 4; ++i) {
        float xv = lx[(tt + i) * XPAD + kk];
        acc[i][0] += xv * wv.x;
        acc[i][1] += xv * wv.y;
        acc[i][2] += xv * wv.z;
        acc[i][3] += xv * wv.w;
      }
    }

    // epilogue: scale + bias + coalesced store to chunked-tmp (in d_out)
    const float rinv = ws[WS_STATS + 2 * (b * NCOLS + j) + 1];
    const float4 bv = *(const float4*)(beta + (size_t)(b * NCOLS + j) * C_DIM + c0 + cc4);
    if (t0 + tt < T_DIM) {
      float* base = out + (size_t)(b * C_DIM + c0 + cc4) * SLAB
                        + q * CHUNK_ELEMS + j * Tp + tp;
      #pragma unroll
      for (int cv = 0; cv < 4; ++cv) {
        const float bb = (&bv.x)[cv];
        float4 v = make_float4(rinv * acc[0][cv] + bb,
                               rinv * acc[1][cv] + bb,
                               rinv * acc[2][cv] + bb,
                               rinv * acc[3][cv] + bb);
        *(float4*)(base + (size_t)cv * SLAB) = v;
      }
    }
    __syncthreads();  // protect LDS before next col's staging
  }
}

// ---------------- pass 2: in-place per-chunk transpose [34][Tp] -> [Tp][34] ----------------
#define TRPAD 35

template <int T4>
__device__ __forceinline__ void trp_load(const float* slab, float* ls, int tid) {
  const int Tp = T4 << 2;
  for (int u = tid; u < NCOLS * T4; u += 256) {
    int jj = u / T4;
    int s  = (u - jj * T4) << 2;
    float4 v = *(const float4*)(slab + jj * Tp + s);
    ls[(s    ) * TRPAD + jj] = v.x;
    ls[(s + 1) * TRPAD + jj] = v.y;
    ls[(s + 2) * TRPAD + jj] = v.z;
    ls[(s + 3) * TRPAD + jj] = v.w;
  }
}

__global__ __launch_bounds__(256) void transpose_k(float* __restrict__ out) {
  __shared__ float ls[CHUNK_T * TRPAD];   // 35840 B
  const int q  = blockIdx.x;
  const int c  = blockIdx.y;
  const int b  = blockIdx.z;
  const int Tp = (q < 7) ? CHUNK_T : LAST_T;
  float* slab = out + (size_t)(b * C_DIM + c) * SLAB + q * CHUNK_ELEMS;
  const int tid = threadIdx.x;

  if (Tp == CHUNK_T) trp_load<CHUNK_T / 4>(slab, ls, tid);
  else               trp_load<LAST_T / 4>(slab, ls, tid);
  __syncthreads();

  const int nf4 = (Tp * NCOLS) >> 2;
  for (int u = tid; u < nf4; u += 256) {
    const int f = u << 2;
    float4 v;
    #pragma unroll
    for (int e = 0; e < 4; ++e) {
      const int fe = f + e;
      const int te = fe / NCOLS;          // const-div -> magic mul
      const int je = fe - te * NCOLS;
      (&v.x)[e] = ls[te * TRPAD + je];
    }
    *(float4*)(slab + f) = v;
  }
}

extern "C" void kernel_launch(void* const* d_in, const int* in_sizes, int n_in,
                              void* d_out, int out_size, void* d_ws, size_t ws_size,
                              hipStream_t stream) {
  const float* x = (const float*)d_in[0];
  float* ws = (float*)d_ws;
  float* out = (float*)d_out;

  stats_k<<<dim3(NCOLS, 8), 512, 0, stream>>>(x, ws);
  prep_k<<<NCOLS, 128, 0, stream>>>(
      (const float*)d_in[1],  (const float*)d_in[2],  (const float*)d_in[3],  (const float*)d_in[4],
      (const float*)d_in[5],  (const float*)d_in[6],  (const float*)d_in[7],  (const float*)d_in[8],
      (const float*)d_in[9],  (const float*)d_in[10], (const float*)d_in[11], (const float*)d_in[12],
      (const float*)d_in[13], (const float*)d_in[14], (const float*)d_in[15], (const float*)d_in[16],
      (const float*)d_in[17], (const float*)d_in[18], (const float*)d_in[19], (const float*)d_in[20],
      ws);
  main_k<<<dim3((T_DIM + TT - 1) / TT, C_DIM / CC, 8), 256, 0, stream>>>(x, ws, out);
  transpose_k<<<dim3(8, C_DIM, 8), 256, 0, stream>>>(out);
}

// Round 3
// 619.147 us; speedup vs baseline: 2.5612x; 1.2744x over previous
//
#include <hip/hip_runtime.h>

// BandSplit: x(8,2000,481,2) f32 -> out(8,128,2000,34) f32
// out[b,c,t,j] = rinv[b,j] * dot(x[b,t,seg_j], CW_j[c,:]) + beta[b,j,c]
//   CW = nw*fw,  beta = fb + S1 - mu*rinv*S2,  S1=dot(nb,fw), S2=dot(nw,fw)
//
// stats_partial_k: full-row coalesced reads, per-block segmented reduce,
//   atomicAdd partials into ws (zeroed by hipMemsetAsync).
// prep_k: finalizes mu/rinv from partials, builds CW (k-major) + beta.
// main_k: tiled GEMM, stores chunked-transposed tmp layout in d_out.
// transpose_k: per-chunk in-place [34][Tp] -> [Tp][34].

#define T_DIM 2000
#define C_DIM 128
#define K_DIM 962
#define NCOLS 34
#define EPSV 1e-5f
#define SLAB 68000        // 2000*34 floats per (b,c)
#define CHUNK_T 256
#define CHUNK_ELEMS (NCOLS * CHUNK_T)   // 8704
#define LAST_T 208        // 2000 - 7*256

#define WS_ACCUM 0                   // 8*34*2 = 544 floats (raw s, s2)
#define WS_STATS 544                 // 8*34*2 = 544 floats (mu, rinv)
#define WS_CW    1088                // 962*128 floats
#define WS_BETA  (1088 + 962*128)    // 8*34*128 floats
// total = 159,040 floats = 636,160 bytes

__constant__ int COL_K0[NCOLS] = {
  0,
  10,18,26,34,42,50,58,66,74,82,90,98,106,114,122,130,138,146,154,
  162,182,202,222,242,262,
  282,362,442,522,602,682,762,
  842};
__constant__ int COL_W[NCOLS] = {
  10,
  8,8,8,8,8,8,8,8,8,8,8,8,8,8,8,8,8,8,8,
  20,20,20,20,20,20,
  80,80,80,80,80,80,80,
  120};
__constant__ int COL_G[NCOLS] = {
  0,
  1,1,1,1,1,1,1,1,1,1,1,1,1,1,1,1,1,1,1,
  2,2,2,2,2,2,
  3,3,3,3,3,3,3,
  4};
__constant__ int COL_NI[NCOLS] = {
  0,
  0,1,2,3,4,5,6,7,8,9,10,11,12,13,14,15,16,17,18,
  0,1,2,3,4,5,
  0,1,2,3,4,5,6,
  0};

// ---------------- stats partial: coalesced full-row read, segmented reduce ----------------
#define SROWS 8
#define BLKS_PER_B (T_DIM / SROWS)   // 250

__global__ __launch_bounds__(512) void stats_partial_k(const float* __restrict__ x,
                                                       float* __restrict__ ws) {
  const int blk = blockIdx.x;
  const int b  = blk / BLKS_PER_B;
  const int r0 = (blk - b * BLKS_PER_B) * SROWS;
  const int tid = threadIdx.x;

  float s = 0.f, s2 = 0.f;
  if (tid < 481) {
    const float* p = x + ((size_t)b * T_DIM + r0) * K_DIM + 2 * tid;
    #pragma unroll
    for (int r = 0; r < SROWS; ++r) {
      float2 v = *(const float2*)p;
      s  += v.x + v.y;
      s2 += v.x * v.x + v.y * v.y;
      p += K_DIM;
    }
  }
  __shared__ float ls[481];
  __shared__ float lq[481];
  if (tid < 481) { ls[tid] = s; lq[tid] = s2; }
  __syncthreads();
  if (tid < NCOLS) {
    const int h0 = COL_K0[tid] >> 1, hw = COL_W[tid] >> 1;
    float a = 0.f, aq = 0.f;
    for (int i = 0; i < hw; ++i) { a += ls[h0 + i]; aq += lq[h0 + i]; }
    atomicAdd(&ws[WS_ACCUM + 2 * (b * NCOLS + tid)],     a);
    atomicAdd(&ws[WS_ACCUM + 2 * (b * NCOLS + tid) + 1], aq);
  }
}

// ---------------- prep: finalize stats, CW[k][c] = nw*fw (k-major), beta ----------------
__global__ __launch_bounds__(128) void prep_k(
    const float* __restrict__ nw0, const float* __restrict__ nb0,
    const float* __restrict__ fw0, const float* __restrict__ fb0,
    const float* __restrict__ nw1, const float* __restrict__ nb1,
    const float* __restrict__ fw1, const float* __restrict__ fb1,
    const float* __restrict__ nw2, const float* __restrict__ nb2,
    const float* __restrict__ fw2, const float* __restrict__ fb2,
    const float* __restrict__ nw3, const float* __restrict__ nb3,
    const float* __restrict__ fw3, const float* __restrict__ fb3,
    const float* __restrict__ nw4, const float* __restrict__ nb4,
    const float* __restrict__ fw4, const float* __restrict__ fb4,
    float* __restrict__ ws) {
  const int j = blockIdx.x, c = threadIdx.x;
  const int g = COL_G[j], ni = COL_NI[j], w = COL_W[j], k0 = COL_K0[j];

  __shared__ float smu[8], srinv[8];
  if (c < 8) {
    float sum = ws[WS_ACCUM + 2 * (c * NCOLS + j)];
    float sq  = ws[WS_ACCUM + 2 * (c * NCOLS + j) + 1];
    float n = (float)(T_DIM * w);
    float mu = sum / n;
    float var = sq / n - mu * mu;
    float rinv = rsqrtf(var + EPSV);
    smu[c] = mu; srinv[c] = rinv;
    ws[WS_STATS + 2 * (c * NCOLS + j)]     = mu;
    ws[WS_STATS + 2 * (c * NCOLS + j) + 1] = rinv;
  }
  __syncthreads();

  const float *nw, *nb, *fw, *fb;
  switch (g) {
    case 0: nw = nw0; nb = nb0; fw = fw0; fb = fb0; break;
    case 1: nw = nw1; nb = nb1; fw = fw1; fb = fb1; break;
    case 2: nw = nw2; nb = nb2; fw = fw2; fb = fb2; break;
    case 3: nw = nw3; nb = nb3; fw = fw3; fb = fb3; break;
    default: nw = nw4; nb = nb4; fw = fw4; fb = fb4; break;
  }
  const float* fwr = fw + ((size_t)ni * C_DIM + c) * w;
  const float* nwr = nw + (size_t)ni * w;
  const float* nbr = nb + (size_t)ni * w;
  float s1 = 0.f, s2 = 0.f;
  float* cw = ws + WS_CW;
  for (int i = 0; i < w; ++i) {
    float f = fwr[i];
    float cwv = nwr[i] * f;
    s1 += nbr[i] * f;
    s2 += cwv;
    cw[(size_t)(k0 + i) * C_DIM + c] = cwv;
  }
  float fbv = fb[(size_t)ni * C_DIM + c];
  for (int b = 0; b < 8; ++b) {
    ws[WS_BETA + (size_t)(b * NCOLS + j) * C_DIM + c] =
        fbv + s1 - smu[b] * srinv[b] * s2;
  }
}

// ---------------- pass 1: per block (b, t0:64, c0:64), loop 34 cols ----------------
#define TT 64
#define CC 64
#define XPAD 124   // 64*124*4 = 31744 B

__global__ __launch_bounds__(256) void main_k(const float* __restrict__ x,
                                              const float* __restrict__ ws,
                                              float* __restrict__ out) {
  __shared__ float lx[TT * XPAD];   // 31744 B
  __shared__ float lw[120 * CC];    // 30720 B
  const int tid = threadIdx.x;
  const int t0 = blockIdx.x * TT;
  const int c0 = blockIdx.y * CC;
  const int b  = blockIdx.z;
  const float* xb   = x + (size_t)b * T_DIM * K_DIM;
  const float* cw   = ws + WS_CW;
  const float* beta = ws + WS_BETA;

  const int tt  = (tid >> 4) << 2;  // thread tile t offset 0..60
  const int cc4 = (tid & 15) << 2;  // thread tile c offset 0..60
  const int sr   = tid >> 2;        // x staging row 0..63
  const int ssub = tid & 3;
  const int wr = tid >> 4;          // W staging k row 0..15
  const int wq = (tid & 15) << 2;   // W staging c quad

  const int q  = t0 >> 8;
  const int Tp = (q < 7) ? CHUNK_T : LAST_T;
  const int tp = (t0 & 255) + tt;

  for (int j = 0; j < NCOLS; ++j) {
    const int w = COL_W[j], k0 = COL_K0[j];
    {
      const int hw = w >> 1;
      const int trow = t0 + sr;
      float* dst = lx + sr * XPAD;
      if (trow < T_DIM) {
        const float* src = xb + (size_t)trow * K_DIM + k0;
        for (int ii = ssub; ii < hw; ii += 4) {
          *(float2*)(dst + 2 * ii) = *(const float2*)(src + 2 * ii);
        }
      } else {
        for (int ii = ssub; ii < hw; ii += 4) {
          *(float2*)(dst + 2 * ii) = make_float2(0.f, 0.f);
        }
      }
    }
    for (int i = wr; i < w; i += 16) {
      *(float4*)(lw + i * CC + wq) =
          *(const float4*)(cw + (size_t)(k0 + i) * C_DIM + c0 + wq);
    }
    __syncthreads();

    float acc[4][4] = {};
    int kk = 0;
    for (; kk + 4 <= w; kk += 4) {
      float4 xa[4];
      #pragma unroll
      for (int i = 0; i < 4; ++i)
        xa[i] = *(const float4*)(lx + (tt + i) * XPAD + kk);
      #pragma unroll
      for (int u = 0; u < 4; ++u) {
        float4 wv = *(const float4*)(lw + (kk + u) * CC + cc4);
        #pragma unroll
        for (int i = 0; i < 4; ++i) {
          float xv = (&xa[i].x)[u];
          acc[i][0] += xv * wv.x;
          acc[i][1] += xv * wv.y;
          acc[i][2] += xv * wv.z;
          acc[i][3] += xv * wv.w;
        }
      }
    }
    for (; kk < w; ++kk) {  // remainder (w=10 only)
      float4 wv = *(const float4*)(lw + kk * CC + cc4);
      #pragma unroll
      for (int i = 0; i < 4; ++i) {
        float xv = lx[(tt + i) * XPAD + kk];
        acc[i][0] += xv * wv.x;
        acc[i][1] += xv * wv.y;
        acc[i][2] += xv * wv.z;
        acc[i][3] += xv * wv.w;
      }
    }

    const float rinv = ws[WS_STATS + 2 * (b * NCOLS + j) + 1];
    const float4 bv = *(const float4*)(beta + (size_t)(b * NCOLS + j) * C_DIM + c0 + cc4);
    if (t0 + tt < T_DIM) {
      float* base = out + (size_t)(b * C_DIM + c0 + cc4) * SLAB
                        + q * CHUNK_ELEMS + j * Tp + tp;
      #pragma unroll
      for (int cv = 0; cv < 4; ++cv) {
        const float bb = (&bv.x)[cv];
        float4 v = make_float4(rinv * acc[0][cv] + bb,
                               rinv * acc[1][cv] + bb,
                               rinv * acc[2][cv] + bb,
                               rinv * acc[3][cv] + bb);
        *(float4*)(base + (size_t)cv * SLAB) = v;
      }
    }
    __syncthreads();
  }
}

// ---------------- pass 2: in-place per-chunk transpose [34][Tp] -> [Tp][34] ----------------
#define TRPAD 35

template <int T4>
__device__ __forceinline__ void trp_load(const float* slab, float* ls, int tid) {
  const int Tp = T4 << 2;
  for (int u = tid; u < NCOLS * T4; u += 256) {
    int jj = u / T4;
    int s  = (u - jj * T4) << 2;
    float4 v = *(const float4*)(slab + jj * Tp + s);
    ls[(s    ) * TRPAD + jj] = v.x;
    ls[(s + 1) * TRPAD + jj] = v.y;
    ls[(s + 2) * TRPAD + jj] = v.z;
    ls[(s + 3) * TRPAD + jj] = v.w;
  }
}

__global__ __launch_bounds__(256) void transpose_k(float* __restrict__ out) {
  __shared__ float ls[CHUNK_T * TRPAD];   // 35840 B
  const int q  = blockIdx.x;
  const int c  = blockIdx.y;
  const int b  = blockIdx.z;
  const int Tp = (q < 7) ? CHUNK_T : LAST_T;
  float* slab = out + (size_t)(b * C_DIM + c) * SLAB + q * CHUNK_ELEMS;
  const int tid = threadIdx.x;

  if (Tp == CHUNK_T) trp_load<CHUNK_T / 4>(slab, ls, tid);
  else               trp_load<LAST_T / 4>(slab, ls, tid);
  __syncthreads();

  const int nf4 = (Tp * NCOLS) >> 2;
  for (int u = tid; u < nf4; u += 256) {
    const int f = u << 2;
    float4 v;
    #pragma unroll
    for (int e = 0; e < 4; ++e) {
      const int fe = f + e;
      const int te = fe / NCOLS;
      const int je = fe - te * NCOLS;
      (&v.x)[e] = ls[te * TRPAD + je];
    }
    *(float4*)(slab + f) = v;
  }
}

extern "C" void kernel_launch(void* const* d_in, const int* in_sizes, int n_in,
                              void* d_out, int out_size, void* d_ws, size_t ws_size,
                              hipStream_t stream) {
  const float* x = (const float*)d_in[0];
  float* ws = (float*)d_ws;
  float* out = (float*)d_out;

  hipMemsetAsync(ws, 0, 544 * sizeof(float), stream);
  stats_partial_k<<<8 * BLKS_PER_B, 512, 0, stream>>>(x, ws);
  prep_k<<<NCOLS, 128, 0, stream>>>(
      (const float*)d_in[1],  (const float*)d_in[2],  (const float*)d_in[3],  (const float*)d_in[4],
      (const float*)d_in[5],  (const float*)d_in[6],  (const float*)d_in[7],  (const float*)d_in[8],
      (const float*)d_in[9],  (const float*)d_in[10], (const float*)d_in[11], (const float*)d_in[12],
      (const float*)d_in[13], (const float*)d_in[14], (const float*)d_in[15], (const float*)d_in[16],
      (const float*)d_in[17], (const float*)d_in[18], (const float*)d_in[19], (const float*)d_in[20],
      ws);
  main_k<<<dim3((T_DIM + TT - 1) / TT, C_DIM / CC, 8), 256, 0, stream>>>(x, ws, out);
  transpose_k<<<dim3(8, C_DIM, 8), 256, 0, stream>>>(out);
}